// Round 7
// baseline (80.776 us; speedup 1.0000x reference)
//
#include <hip/hip_runtime.h>

#define GN 512
#define HH 32
#define DD 64

typedef float v4f __attribute__((ext_vector_type(4)));
typedef unsigned int v4u __attribute__((ext_vector_type(4)));
typedef u_int32_t u32;
typedef u32 v2u __attribute__((ext_vector_type(2)));
typedef __bf16 v8bf __attribute__((ext_vector_type(8)));

__device__ __forceinline__ u32 f2bf(float f) {
  u32 u = __builtin_bit_cast(u32, f);
  return (u + 0x7fffu + ((u >> 16) & 1u)) >> 16;
}
__device__ __forceinline__ u32 pack2(float a, float b) {
  return f2bf(a) | (f2bf(b) << 16);
}

#define GLOAD16(g, l)                                                              \
  __builtin_amdgcn_global_load_lds((const __attribute__((address_space(1))) u32*)(g), \
                                   (__attribute__((address_space(3))) u32*)(l), 16, 0, 0)
#define VMCNT0 asm volatile("s_waitcnt vmcnt(0)" ::: "memory")
#define SCHEDBAR __builtin_amdgcn_sched_barrier(0)

// ---------------- Stage 1: projections -> exp space -------------------------
__global__ __launch_bounds__(256) void kq_kernel(const float* __restrict__ rec,
                                                 const float* __restrict__ att,
                                                 const float* __restrict__ wq,
                                                 const float* __restrict__ wk,
                                                 const float* __restrict__ bias,
                                                 float* __restrict__ ekbuf,
                                                 float* __restrict__ eqbuf) {
  __shared__ float rr[512], ra[512];
  int tid = threadIdx.x;
  size_t base = (size_t)blockIdx.x * 8;
  const float* gr = rec + base * DD;
  const float* ga = att + base * DD;
  rr[tid] = gr[tid]; rr[tid + 256] = gr[tid + 256];
  ra[tid] = ga[tid]; ra[tid + 256] = ga[tid + 256];
  __syncthreads();
  int r = tid >> 5, h = tid & 31;
  float sk = bias[h], sq = 0.f;
  const float* rrow = &rr[r * DD];
  const float* arow = &ra[r * DD];
#pragma unroll 8
  for (int d = 0; d < DD; ++d) {
    sk += rrow[d] * wk[d * HH + h];
    sq += arow[d] * wq[d * HH + h];
  }
  const float C = 2.8853900817779268f;  // 2*log2(e)
  ekbuf[(base + r) * HH + h] = __builtin_exp2f(C * sk);
  eqbuf[(base + r) * HH + h] = __builtin_exp2f(C * sq);
}

// ------- Stage 2+3 fused, phase-inverted: escore first, transpose after -----
// All tiles staged via async global_load_lds at entry; adj HBM latency+BW
// hides under escore's long VALU phase. Chunk-XOR swizzles (source-side)
// keep every LDS read <=2-way or conflict-free.
__global__ __launch_bounds__(256) void prep_kernel(const float* __restrict__ adj,
                                                   const float* __restrict__ ek,
                                                   const float* __restrict__ eq,
                                                   const float* __restrict__ avec,
                                                   unsigned short* __restrict__ adjT,
                                                   unsigned short* __restrict__ adjBF,
                                                   unsigned short* __restrict__ Et) {
  __shared__ __align__(16) float tA[64 * 64];  // adj tile, 16-chunk XOR swizzle
  __shared__ __align__(16) float kl[64 * 32];  // ek tile, 8-chunk XOR swizzle
  __shared__ __align__(16) float ql[64 * 32];  // eq tile, 8-chunk XOR swizzle

  int tid = threadIdx.x, wave = tid >> 6;
  int b = blockIdx.z;
  int n0 = blockIdx.x * 64, m0 = blockIdx.y * 64;
  int c0 = n0, r0 = m0;

  // uniform a-vector (likely s_load; issued before gloads either way)
  v4f a2v[8];
  float asum = 0.f;
#pragma unroll
  for (int h4 = 0; h4 < 8; ++h4) {
    v4f av = *(const v4f*)(avec + h4 * 4);
    a2v[h4] = av * 2.0f;
    asum += av[0] + av[1] + av[2] + av[3];
  }
  SCHEDBAR;

  // async stage kl/ql: rows of 32 f32 = 8 chunks; phys slot p holds global
  // chunk p^(r&7); linear LDS dest (wave base + lane*16).
  const float* kb = ek + ((size_t)b * GN + n0) * HH;
  const float* qb = eq + ((size_t)b * GN + m0) * HH;
#pragma unroll
  for (int i = 0; i < 2; ++i) {
    int c = i * 256 + tid;  // 0..511
    int r = c >> 3, g = (c & 7) ^ (r & 7);
    GLOAD16(kb + r * HH + g * 4, (char*)kl + (i * 256 + wave * 64) * 16);
    GLOAD16(qb + r * HH + g * 4, (char*)ql + (i * 256 + wave * 64) * 16);
  }
  SCHEDBAR;
  // async stage adj tile: rows of 64 f32 = 16 chunks; slot p <- chunk p^(r&15)
  const float* ab = adj + (size_t)b * GN * GN;
#pragma unroll
  for (int i = 0; i < 4; ++i) {
    int c = i * 256 + tid;  // 0..1023
    int r = c >> 4, g = (c & 15) ^ (r & 15);
    GLOAD16(ab + (size_t)(r0 + r) * GN + c0 + g * 4, (char*)tA + (i * 256 + wave * 64) * 16);
  }
  SCHEDBAR;
  asm volatile("s_waitcnt vmcnt(4)" ::: "memory");  // kl/ql landed; tA in flight
  __builtin_amdgcn_s_barrier();
  SCHEDBAR;

  // ---- phase B: escore ----
  int m = tid >> 2, ng = tid & 3;
  v4f qv[8];
#pragma unroll
  for (int h4 = 0; h4 < 8; ++h4)
    qv[h4] = *(const v4f*)&ql[m * HH + ((h4 ^ (m & 7)) << 2)];
  int x0 = 2 * ng, x1 = 2 * ng + 1;  // (n&7), (n1&7) — nn-invariant
  u32 ow[8];
#pragma unroll
  for (int nn = 0; nn < 8; ++nn) {
    int n = ng * 2 + nn * 8;
    v4f acc0 = (v4f){0.f, 0.f, 0.f, 0.f};
    v4f acc1 = (v4f){0.f, 0.f, 0.f, 0.f};
#pragma unroll
    for (int h4 = 0; h4 < 8; ++h4) {
      v4f kv0 = *(const v4f*)&kl[n * HH + ((h4 ^ x0) << 2)];
      v4f kv1 = *(const v4f*)&kl[(n + 1) * HH + ((h4 ^ x1) << 2)];
      v4f f0 = kv0 * qv[h4] + 1.0f;
      v4f f1 = kv1 * qv[h4] + 1.0f;
      v4f r0v, r1v;
#pragma unroll
      for (int e = 0; e < 4; ++e) {
        r0v[e] = __builtin_amdgcn_rcpf(f0[e]);
        r1v[e] = __builtin_amdgcn_rcpf(f1[e]);
      }
      acc0 += a2v[h4] * r0v;
      acc1 += a2v[h4] * r1v;
    }
    float s0 = asum - (acc0[0] + acc0[1] + acc0[2] + acc0[3]);
    float s1 = asum - (acc1[0] + acc1[1] + acc1[2] + acc1[3]);
    ow[nn] = pack2(s0, s1);
  }

  VMCNT0;  // tA gloads complete (long since landed under phase B)
  __builtin_amdgcn_s_barrier();
  SCHEDBAR;

  // ---- phase A: emit adjBF (row-major bf16) + adjT (transposed bf16) ----
  unsigned short* of = adjBF + (size_t)b * GN * GN;
#pragma unroll
  for (int i = 0; i < 4; ++i) {
    int c = i * 256 + tid;
    int r = c >> 4, g = (c & 15) ^ (r & 15);
    v4f f = *(const v4f*)&tA[c * 4];  // linear b128, own chunk
    v2u pk = {pack2(f[0], f[1]), pack2(f[2], f[3])};
    *(v2u*)(of + (size_t)(r0 + r) * GN + c0 + g * 4) = pk;
  }
  {
    unsigned short* ob = adjT + (size_t)b * GN * GN;
    int col = tid & 63, rs = (tid >> 6) * 16;  // rs wave-uniform: 2-way max
    int gc = col >> 2, ce = col & 3;
    u32 qq[8];
#pragma unroll
    for (int j = 0; j < 8; ++j) {
      int R0 = rs + 2 * j, R1 = R0 + 1;
      float v0 = tA[R0 * 64 + ((gc ^ (R0 & 15)) << 2) + ce];
      float v1 = tA[R1 * 64 + ((gc ^ (R1 & 15)) << 2) + ce];
      qq[j] = pack2(v0, v1);
    }
    unsigned short* dst = ob + (size_t)(c0 + col) * GN + r0 + rs;
    *(v4u*)dst = (v4u){qq[0], qq[1], qq[2], qq[3]};
    *(v4u*)(dst + 8) = (v4u){qq[4], qq[5], qq[6], qq[7]};
  }
  // ---- Et store (deferred; fire-and-forget) ----
  u32* dstw = (u32*)(Et + ((size_t)b * GN + m0 + m) * GN + n0);
#pragma unroll
  for (int nn = 0; nn < 8; ++nn) dstw[ng + nn * 4] = ow[nn];
}

// ---------------- Stage 4/5: batched bf16 GEMM, 2-phase + XCD swizzle -------
#define SWZ(r, s) ((s) ^ ((r) & 7))

template <bool OUTF32>
__global__ __launch_bounds__(256) void gemm_bt(const unsigned short* __restrict__ A,
                                               const unsigned short* __restrict__ Bt,
                                               void* __restrict__ Cv) {
  __shared__ unsigned short At[2][128 * 64];  // 2 x 16 KiB
  __shared__ unsigned short Bs[2][128 * 64];
  int bid = blockIdx.x;
  int swz = (bid & 7) * 64 + (bid >> 3);  // XCD-chunked, bijective
  int b = swz >> 4;
  int row0 = ((swz >> 2) & 3) * 128;
  int col0 = (swz & 3) * 128;
  int tid = threadIdx.x, lane = tid & 63, wave = tid >> 6;
  int wr = wave >> 1, wc = wave & 1;
  const unsigned short* Ab = A + (size_t)b * GN * GN;
  const unsigned short* Bb = Bt + (size_t)b * GN * GN;

  v4f acc[4][4];
#pragma unroll
  for (int i = 0; i < 4; ++i)
#pragma unroll
    for (int j = 0; j < 4; ++j) acc[i][j] = (v4f){0.f, 0.f, 0.f, 0.f};

  int cc_r[4], cc_s[4];
#pragma unroll
  for (int i = 0; i < 4; ++i) {
    int c = i * 256 + tid;
    cc_r[i] = c >> 3;
    cc_s[i] = SWZ(c >> 3, c & 7);
  }

#define STAGE(buf, kt)                                                                   \
  {                                                                                      \
    _Pragma("unroll") for (int i = 0; i < 4; ++i) {                                      \
      const unsigned short* ga = Ab + (size_t)(row0 + cc_r[i]) * GN + (kt)*64 + cc_s[i] * 8; \
      const unsigned short* gb = Bb + (size_t)(col0 + cc_r[i]) * GN + (kt)*64 + cc_s[i] * 8; \
      GLOAD16(ga, (char*)&At[buf][0] + (i * 256 + wave * 64) * 16);                      \
      GLOAD16(gb, (char*)&Bs[buf][0] + (i * 256 + wave * 64) * 16);                      \
    }                                                                                    \
  }

#define COMPUTE(buf)                                                                     \
  {                                                                                      \
    int lr = lane & 15, s16 = lane >> 4;                                                 \
    _Pragma("unroll") for (int h = 0; h < 2; ++h) {                                      \
      int sl = h * 4 + s16;                                                              \
      v8bf af[4], bfv[4];                                                                \
      _Pragma("unroll") for (int i = 0; i < 4; ++i) {                                    \
        int r = wr * 64 + i * 16 + lr;                                                   \
        af[i] = *(const v8bf*)&At[buf][r * 64 + SWZ(r, sl) * 8];                         \
      }                                                                                  \
      _Pragma("unroll") for (int j = 0; j < 4; ++j) {                                    \
        int r = wc * 64 + j * 16 + lr;                                                   \
        bfv[j] = *(const v8bf*)&Bs[buf][r * 64 + SWZ(r, sl) * 8];                        \
      }                                                                                  \
      _Pragma("unroll") for (int i = 0; i < 4; ++i)                                      \
          _Pragma("unroll") for (int j = 0; j < 4; ++j) acc[i][j] =                      \
          __builtin_amdgcn_mfma_f32_16x16x32_bf16(af[i], bfv[j], acc[i][j], 0, 0, 0);    \
    }                                                                                    \
  }

  STAGE(0, 0);
  VMCNT0;
  __builtin_amdgcn_s_barrier();
#pragma unroll
  for (int kt = 0; kt < 7; ++kt) {
    int cur = kt & 1;
    STAGE(cur ^ 1, kt + 1);
    COMPUTE(cur);
    VMCNT0;
    __builtin_amdgcn_s_barrier();
  }
  COMPUTE(1);

  int lc = lane & 15;
  int lrow4 = (lane >> 4) * 4;
#pragma unroll
  for (int i = 0; i < 4; ++i) {
#pragma unroll
    for (int j = 0; j < 4; ++j) {
      int gr = row0 + wr * 64 + i * 16 + lrow4;
      int gc = col0 + wc * 64 + j * 16 + lc;
#pragma unroll
      for (int e = 0; e < 4; ++e) {
        float v = acc[i][j][e];
        if constexpr (OUTF32)
          ((float*)Cv)[(size_t)b * GN * GN + (size_t)(gr + e) * GN + gc] = v;
        else
          ((unsigned short*)Cv)[(size_t)b * GN * GN + (size_t)(gr + e) * GN + gc] =
              (unsigned short)f2bf(v);
      }
    }
  }
#undef STAGE
#undef COMPUTE
}

// ---------------- launch ----------------------------------------------------
extern "C" void kernel_launch(void* const* d_in, const int* in_sizes, int n_in,
                              void* d_out, int out_size, void* d_ws, size_t ws_size,
                              hipStream_t stream) {
  const float* receiver  = (const float*)d_in[0];
  const float* attendant = (const float*)d_in[1];
  const float* adj       = (const float*)d_in[2];
  const float* wq        = (const float*)d_in[3];
  const float* wk        = (const float*)d_in[4];
  const float* bias      = (const float*)d_in[5];
  const float* avec      = (const float*)d_in[6];
  float* out = (float*)d_out;

  char* ws = (char*)d_ws;
  float* ekbuf          = (float*)(ws);                          // 2 MiB
  float* eqbuf          = (float*)(ws + (2u << 20));             // 2 MiB
  unsigned short* Et    = (unsigned short*)(ws + (4u << 20));    // 16 MiB
  unsigned short* adjT  = (unsigned short*)(ws + (20u << 20));   // 16 MiB
  unsigned short* adjBF = (unsigned short*)(ws + (36u << 20));   // 16 MiB
  unsigned short* Tbuf  = (unsigned short*)(ws + (52u << 20));   // 16 MiB

  kq_kernel<<<dim3(2048), dim3(256), 0, stream>>>(receiver, attendant, wq, wk, bias,
                                                  ekbuf, eqbuf);
  prep_kernel<<<dim3(8, 8, 32), dim3(256), 0, stream>>>(adj, ekbuf, eqbuf, avec,
                                                        adjT, adjBF, Et);
  // T = adjBF @ Et^T  -> bf16
  gemm_bt<false><<<dim3(512), dim3(256), 0, stream>>>(adjBF, Et, Tbuf);
  // out = Tbuf @ adjT^T -> f32
  gemm_bt<true><<<dim3(512), dim3(256), 0, stream>>>(Tbuf, adjT, out);
}

// Round 8
// 79.759 us; speedup vs baseline: 1.0128x; 1.0128x over previous
//
#include <hip/hip_runtime.h>

#define GN 512
#define HH 32
#define DD 64

typedef float v4f __attribute__((ext_vector_type(4)));
typedef unsigned int v4u __attribute__((ext_vector_type(4)));
typedef u_int32_t u32;
typedef u32 v2u __attribute__((ext_vector_type(2)));
typedef __bf16 v8bf __attribute__((ext_vector_type(8)));

__device__ __forceinline__ u32 f2bf(float f) {
  u32 u = __builtin_bit_cast(u32, f);
  return (u + 0x7fffu + ((u >> 16) & 1u)) >> 16;
}
__device__ __forceinline__ u32 pack2(float a, float b) {
  return f2bf(a) | (f2bf(b) << 16);
}

#define GLOAD16(g, l)                                                              \
  __builtin_amdgcn_global_load_lds((const __attribute__((address_space(1))) u32*)(g), \
                                   (__attribute__((address_space(3))) u32*)(l), 16, 0, 0)
#define VMCNT0 asm volatile("s_waitcnt vmcnt(0)" ::: "memory")
#define SCHEDBAR __builtin_amdgcn_sched_barrier(0)

// ---------------- Stage 1: projections -> exp space -------------------------
__global__ __launch_bounds__(256) void kq_kernel(const float* __restrict__ rec,
                                                 const float* __restrict__ att,
                                                 const float* __restrict__ wq,
                                                 const float* __restrict__ wk,
                                                 const float* __restrict__ bias,
                                                 float* __restrict__ ekbuf,
                                                 float* __restrict__ eqbuf) {
  __shared__ float rr[512], ra[512];
  int tid = threadIdx.x;
  size_t base = (size_t)blockIdx.x * 8;
  const float* gr = rec + base * DD;
  const float* ga = att + base * DD;
  rr[tid] = gr[tid]; rr[tid + 256] = gr[tid + 256];
  ra[tid] = ga[tid]; ra[tid + 256] = ga[tid + 256];
  __syncthreads();
  int r = tid >> 5, h = tid & 31;
  float sk = bias[h], sq = 0.f;
  const float* rrow = &rr[r * DD];
  const float* arow = &ra[r * DD];
#pragma unroll 8
  for (int d = 0; d < DD; ++d) {
    sk += rrow[d] * wk[d * HH + h];
    sq += arow[d] * wq[d * HH + h];
  }
  const float C = 2.8853900817779268f;  // 2*log2(e)
  ekbuf[(base + r) * HH + h] = __builtin_exp2f(C * sk);
  eqbuf[(base + r) * HH + h] = __builtin_exp2f(C * sq);
}

// ------- Stage 2+3 fused: escore (4x4 register-blocked) + transpose ---------
// kl/ql in padded LDS (row stride 36 f32): inner loop is pure
// ds_read_b128(base, imm-offset) + fma + rcp — no addressing VALU.
// adj tile async-staged (global_load_lds, XOR chunks), consumed after escore.
__global__ __launch_bounds__(256) void prep_kernel(const float* __restrict__ adj,
                                                   const float* __restrict__ ek,
                                                   const float* __restrict__ eq,
                                                   const float* __restrict__ avec,
                                                   unsigned short* __restrict__ adjT,
                                                   unsigned short* __restrict__ adjBF,
                                                   unsigned short* __restrict__ Et) {
  __shared__ __align__(16) float tA[64 * 64];   // adj tile (linear + chunk XOR)
  __shared__ __align__(16) float kl[64 * 36];   // padded: bank-spread co-reads
  __shared__ __align__(16) float ql[64 * 36];

  int tid = threadIdx.x, wave = tid >> 6;
  int b = blockIdx.z;
  int n0 = blockIdx.x * 64, m0 = blockIdx.y * 64;
  int c0 = n0, r0 = m0;

  // ---- issue kl/ql register loads first (vmcnt slots 7..4) ----
  const float* kb = ek + ((size_t)b * GN + n0) * HH;
  const float* qb = eq + ((size_t)b * GN + m0) * HH;
  int sr = tid >> 3, sp = tid & 7;               // chunk tid: row, pos
  v4f rk0 = *(const v4f*)(kb + sr * HH + sp * 4);
  v4f rq0 = *(const v4f*)(qb + sr * HH + sp * 4);
  v4f rk1 = *(const v4f*)(kb + (sr + 32) * HH + sp * 4);
  v4f rq1 = *(const v4f*)(qb + (sr + 32) * HH + sp * 4);
  SCHEDBAR;
  // ---- adj tile async (vmcnt slots 3..0); slot p <- global chunk p^(r&15) ----
  const float* ab = adj + (size_t)b * GN * GN;
#pragma unroll
  for (int i = 0; i < 4; ++i) {
    int c = i * 256 + tid;
    int r = c >> 4, g = (c & 15) ^ (r & 15);
    GLOAD16(ab + (size_t)(r0 + r) * GN + c0 + g * 4, (char*)tA + (i * 256 + wave * 64) * 16);
  }
  SCHEDBAR;

  // uniform a-vector
  float a2s[HH];
  float asum = 0.f;
#pragma unroll
  for (int h = 0; h < HH; ++h) {
    float av = avec[h];
    a2s[h] = 2.0f * av;
    asum += av;
  }

  asm volatile("s_waitcnt vmcnt(4)" ::: "memory");  // rk/rq landed; tA in flight
  *(v4f*)&kl[sr * 36 + sp * 4] = rk0;
  *(v4f*)&ql[sr * 36 + sp * 4] = rq0;
  *(v4f*)&kl[(sr + 32) * 36 + sp * 4] = rk1;
  *(v4f*)&ql[(sr + 32) * 36 + sp * 4] = rq1;
  asm volatile("s_waitcnt lgkmcnt(0)" ::: "memory");
  __builtin_amdgcn_s_barrier();
  SCHEDBAR;

  // ---- phase B: escore, 4m x 4n per thread (stride-16 blocking) ----
  int mg = tid >> 4, ng = tid & 15;
  const float* kvb[4];
  const float* qvb[4];
#pragma unroll
  for (int j = 0; j < 4; ++j) {
    kvb[j] = &kl[(ng + 16 * j) * 36];
    qvb[j] = &ql[(mg + 16 * j) * 36];
  }
  float acc[4][4];
#pragma unroll
  for (int i = 0; i < 4; ++i)
#pragma unroll
    for (int j = 0; j < 4; ++j) acc[i][j] = 0.f;

#pragma unroll
  for (int h4 = 0; h4 < 8; ++h4) {
    v4f kv[4], qv[4];
#pragma unroll
    for (int j = 0; j < 4; ++j) kv[j] = *(const v4f*)(kvb[j] + h4 * 4);
#pragma unroll
    for (int i = 0; i < 4; ++i) qv[i] = *(const v4f*)(qvb[i] + h4 * 4);
#pragma unroll
    for (int i = 0; i < 4; ++i)
#pragma unroll
      for (int j = 0; j < 4; ++j) {
        v4f f = kv[j] * qv[i] + 1.0f;
        acc[i][j] = __builtin_fmaf(a2s[h4 * 4 + 0], __builtin_amdgcn_rcpf(f[0]), acc[i][j]);
        acc[i][j] = __builtin_fmaf(a2s[h4 * 4 + 1], __builtin_amdgcn_rcpf(f[1]), acc[i][j]);
        acc[i][j] = __builtin_fmaf(a2s[h4 * 4 + 2], __builtin_amdgcn_rcpf(f[2]), acc[i][j]);
        acc[i][j] = __builtin_fmaf(a2s[h4 * 4 + 3], __builtin_amdgcn_rcpf(f[3]), acc[i][j]);
      }
  }
  // Et stores: 16 scalar bf16 (rows m0+mg+16i, cols n0+ng+16j)
  unsigned short* eb = Et + ((size_t)b * GN + m0 + mg) * GN + n0 + ng;
#pragma unroll
  for (int i = 0; i < 4; ++i)
#pragma unroll
    for (int j = 0; j < 4; ++j)
      eb[(size_t)(16 * i) * GN + 16 * j] = (unsigned short)f2bf(asum - acc[i][j]);

  VMCNT0;  // tA landed (hidden under escore)
  __builtin_amdgcn_s_barrier();
  SCHEDBAR;

  // ---- phase A: emit adjBF (row-major bf16) + adjT (transposed bf16) ----
  unsigned short* of = adjBF + (size_t)b * GN * GN;
#pragma unroll
  for (int i = 0; i < 4; ++i) {
    int c = i * 256 + tid;
    int r = c >> 4, g = (c & 15) ^ (r & 15);
    v4f f = *(const v4f*)&tA[c * 4];  // linear b128, own chunk
    v2u pk = {pack2(f[0], f[1]), pack2(f[2], f[3])};
    *(v2u*)(of + (size_t)(r0 + r) * GN + c0 + g * 4) = pk;
  }
  {
    unsigned short* ob = adjT + (size_t)b * GN * GN;
    int col = tid & 63, rs = (tid >> 6) * 16;
    int gc = col >> 2, ce = col & 3;
    u32 qq[8];
#pragma unroll
    for (int j = 0; j < 8; ++j) {
      int R0 = rs + 2 * j, R1 = R0 + 1;
      float v0 = tA[R0 * 64 + ((gc ^ (R0 & 15)) << 2) + ce];
      float v1 = tA[R1 * 64 + ((gc ^ (R1 & 15)) << 2) + ce];
      qq[j] = pack2(v0, v1);
    }
    unsigned short* dst = ob + (size_t)(c0 + col) * GN + r0 + rs;
    *(v4u*)dst = (v4u){qq[0], qq[1], qq[2], qq[3]};
    *(v4u*)(dst + 8) = (v4u){qq[4], qq[5], qq[6], qq[7]};
  }
}

// ---------------- Stage 4/5: batched bf16 GEMM, 2-phase + XCD swizzle -------
#define SWZ(r, s) ((s) ^ ((r) & 7))

template <bool OUTF32>
__global__ __launch_bounds__(256) void gemm_bt(const unsigned short* __restrict__ A,
                                               const unsigned short* __restrict__ Bt,
                                               void* __restrict__ Cv) {
  __shared__ unsigned short At[2][128 * 64];  // 2 x 16 KiB
  __shared__ unsigned short Bs[2][128 * 64];
  int bid = blockIdx.x;
  int swz = (bid & 7) * 64 + (bid >> 3);  // XCD-chunked, bijective
  int b = swz >> 4;
  int row0 = ((swz >> 2) & 3) * 128;
  int col0 = (swz & 3) * 128;
  int tid = threadIdx.x, lane = tid & 63, wave = tid >> 6;
  int wr = wave >> 1, wc = wave & 1;
  const unsigned short* Ab = A + (size_t)b * GN * GN;
  const unsigned short* Bb = Bt + (size_t)b * GN * GN;

  v4f acc[4][4];
#pragma unroll
  for (int i = 0; i < 4; ++i)
#pragma unroll
    for (int j = 0; j < 4; ++j) acc[i][j] = (v4f){0.f, 0.f, 0.f, 0.f};

  int cc_r[4], cc_s[4];
#pragma unroll
  for (int i = 0; i < 4; ++i) {
    int c = i * 256 + tid;
    cc_r[i] = c >> 3;
    cc_s[i] = SWZ(c >> 3, c & 7);
  }

#define STAGE(buf, kt)                                                                   \
  {                                                                                      \
    _Pragma("unroll") for (int i = 0; i < 4; ++i) {                                      \
      const unsigned short* ga = Ab + (size_t)(row0 + cc_r[i]) * GN + (kt)*64 + cc_s[i] * 8; \
      const unsigned short* gb = Bb + (size_t)(col0 + cc_r[i]) * GN + (kt)*64 + cc_s[i] * 8; \
      GLOAD16(ga, (char*)&At[buf][0] + (i * 256 + wave * 64) * 16);                      \
      GLOAD16(gb, (char*)&Bs[buf][0] + (i * 256 + wave * 64) * 16);                      \
    }                                                                                    \
  }

#define COMPUTE(buf)                                                                     \
  {                                                                                      \
    int lr = lane & 15, s16 = lane >> 4;                                                 \
    _Pragma("unroll") for (int h = 0; h < 2; ++h) {                                      \
      int sl = h * 4 + s16;                                                              \
      v8bf af[4], bfv[4];                                                                \
      _Pragma("unroll") for (int i = 0; i < 4; ++i) {                                    \
        int r = wr * 64 + i * 16 + lr;                                                   \
        af[i] = *(const v8bf*)&At[buf][r * 64 + SWZ(r, sl) * 8];                         \
      }                                                                                  \
      _Pragma("unroll") for (int j = 0; j < 4; ++j) {                                    \
        int r = wc * 64 + j * 16 + lr;                                                   \
        bfv[j] = *(const v8bf*)&Bs[buf][r * 64 + SWZ(r, sl) * 8];                        \
      }                                                                                  \
      _Pragma("unroll") for (int i = 0; i < 4; ++i)                                      \
          _Pragma("unroll") for (int j = 0; j < 4; ++j) acc[i][j] =                      \
          __builtin_amdgcn_mfma_f32_16x16x32_bf16(af[i], bfv[j], acc[i][j], 0, 0, 0);    \
    }                                                                                    \
  }

  STAGE(0, 0);
  VMCNT0;
  __builtin_amdgcn_s_barrier();
#pragma unroll
  for (int kt = 0; kt < 7; ++kt) {
    int cur = kt & 1;
    STAGE(cur ^ 1, kt + 1);
    COMPUTE(cur);
    VMCNT0;
    __builtin_amdgcn_s_barrier();
  }
  COMPUTE(1);

  int lc = lane & 15;
  int lrow4 = (lane >> 4) * 4;
#pragma unroll
  for (int i = 0; i < 4; ++i) {
#pragma unroll
    for (int j = 0; j < 4; ++j) {
      int gr = row0 + wr * 64 + i * 16 + lrow4;
      int gc = col0 + wc * 64 + j * 16 + lc;
#pragma unroll
      for (int e = 0; e < 4; ++e) {
        float v = acc[i][j][e];
        if constexpr (OUTF32)
          ((float*)Cv)[(size_t)b * GN * GN + (size_t)(gr + e) * GN + gc] = v;
        else
          ((unsigned short*)Cv)[(size_t)b * GN * GN + (size_t)(gr + e) * GN + gc] =
              (unsigned short)f2bf(v);
      }
    }
  }
#undef STAGE
#undef COMPUTE
}

// ---------------- launch ----------------------------------------------------
extern "C" void kernel_launch(void* const* d_in, const int* in_sizes, int n_in,
                              void* d_out, int out_size, void* d_ws, size_t ws_size,
                              hipStream_t stream) {
  const float* receiver  = (const float*)d_in[0];
  const float* attendant = (const float*)d_in[1];
  const float* adj       = (const float*)d_in[2];
  const float* wq        = (const float*)d_in[3];
  const float* wk        = (const float*)d_in[4];
  const float* bias      = (const float*)d_in[5];
  const float* avec      = (const float*)d_in[6];
  float* out = (float*)d_out;

  char* ws = (char*)d_ws;
  float* ekbuf          = (float*)(ws);                          // 2 MiB
  float* eqbuf          = (float*)(ws + (2u << 20));             // 2 MiB
  unsigned short* Et    = (unsigned short*)(ws + (4u << 20));    // 16 MiB
  unsigned short* adjT  = (unsigned short*)(ws + (20u << 20));   // 16 MiB
  unsigned short* adjBF = (unsigned short*)(ws + (36u << 20));   // 16 MiB
  unsigned short* Tbuf  = (unsigned short*)(ws + (52u << 20));   // 16 MiB

  kq_kernel<<<dim3(2048), dim3(256), 0, stream>>>(receiver, attendant, wq, wk, bias,
                                                  ekbuf, eqbuf);
  prep_kernel<<<dim3(8, 8, 32), dim3(256), 0, stream>>>(adj, ekbuf, eqbuf, avec,
                                                        adjT, adjBF, Et);
  // T = adjBF @ Et^T  -> bf16
  gemm_bt<false><<<dim3(512), dim3(256), 0, stream>>>(adjBF, Et, Tbuf);
  // out = Tbuf @ adjT^T -> f32
  gemm_bt<true><<<dim3(512), dim3(256), 0, stream>>>(Tbuf, adjT, out);
}

// Round 9
// 78.419 us; speedup vs baseline: 1.0300x; 1.0171x over previous
//
#include <hip/hip_runtime.h>

#define GN 512
#define HH 32
#define DD 64

typedef float v4f __attribute__((ext_vector_type(4)));
typedef unsigned int v4u __attribute__((ext_vector_type(4)));
typedef u_int32_t u32;
typedef u32 v2u __attribute__((ext_vector_type(2)));
typedef __bf16 v8bf __attribute__((ext_vector_type(8)));

__device__ __forceinline__ u32 f2bf(float f) {
  u32 u = __builtin_bit_cast(u32, f);
  return (u + 0x7fffu + ((u >> 16) & 1u)) >> 16;
}
__device__ __forceinline__ u32 pack2(float a, float b) {
  return f2bf(a) | (f2bf(b) << 16);
}

#define GLOAD16(g, l)                                                              \
  __builtin_amdgcn_global_load_lds((const __attribute__((address_space(1))) u32*)(g), \
                                   (__attribute__((address_space(3))) u32*)(l), 16, 0, 0)
#define VMCNT0 asm volatile("s_waitcnt vmcnt(0)" ::: "memory")

// ---------------- Stage 1: projections -> exp space -------------------------
__global__ __launch_bounds__(256) void kq_kernel(const float* __restrict__ rec,
                                                 const float* __restrict__ att,
                                                 const float* __restrict__ wq,
                                                 const float* __restrict__ wk,
                                                 const float* __restrict__ bias,
                                                 float* __restrict__ ekbuf,
                                                 float* __restrict__ eqbuf) {
  __shared__ float rr[512], ra[512];
  int tid = threadIdx.x;
  size_t base = (size_t)blockIdx.x * 8;
  const float* gr = rec + base * DD;
  const float* ga = att + base * DD;
  rr[tid] = gr[tid]; rr[tid + 256] = gr[tid + 256];
  ra[tid] = ga[tid]; ra[tid + 256] = ga[tid + 256];
  __syncthreads();
  int r = tid >> 5, h = tid & 31;
  float sk = bias[h], sq = 0.f;
  const float* rrow = &rr[r * DD];
  const float* arow = &ra[r * DD];
#pragma unroll 8
  for (int d = 0; d < DD; ++d) {
    sk += rrow[d] * wk[d * HH + h];
    sq += arow[d] * wq[d * HH + h];
  }
  const float C = 2.8853900817779268f;  // 2*log2(e)
  ekbuf[(base + r) * HH + h] = __builtin_exp2f(C * sk);
  eqbuf[(base + r) * HH + h] = __builtin_exp2f(C * sq);
}

// ------- Stage 2+3: heterogeneous blocks — escore OR transpose --------------
// bid%5 < 4  -> escore block: one 64x64 (m,n) tile, paired-rcp math.
// bid%5 == 4 -> transpose block: four 64x64 adj tiles -> adjT + adjBF.
// Mixing block types on each CU overlaps escore's VALU/trans pipes with the
// transpose's HBM traffic (TLP overlap, not phase fusion).
__global__ __launch_bounds__(256) void prep2_kernel(const float* __restrict__ adj,
                                                    const float* __restrict__ ek,
                                                    const float* __restrict__ eq,
                                                    const float* __restrict__ avec,
                                                    unsigned short* __restrict__ adjT,
                                                    unsigned short* __restrict__ adjBF,
                                                    unsigned short* __restrict__ Et) {
  __shared__ __align__(16) float smem[4608];  // escore: kl|ql ; transpose: t[64][65]
  int tid = threadIdx.x;
  int bid = blockIdx.x;
  int type = bid % 5, grp = bid / 5;

  if (type < 4) {
    // ================= escore block =================
    float (*kl)[36] = (float (*)[36])smem;
    float (*ql)[36] = (float (*)[36])&smem[64 * 36];
    int e = grp * 4 + type;
    int b = e >> 6, rem = e & 63;
    int n0 = (rem & 7) * 64, m0 = (rem >> 3) * 64;

    const float* kb = ek + ((size_t)b * GN + n0) * HH;
    const float* qb = eq + ((size_t)b * GN + m0) * HH;
    int sr = tid >> 3, sp = tid & 7;
    v4f rk0 = *(const v4f*)(kb + sr * HH + sp * 4);
    v4f rq0 = *(const v4f*)(qb + sr * HH + sp * 4);
    v4f rk1 = *(const v4f*)(kb + (sr + 32) * HH + sp * 4);
    v4f rq1 = *(const v4f*)(qb + (sr + 32) * HH + sp * 4);
    *(v4f*)&kl[sr][sp * 4] = rk0;
    *(v4f*)&ql[sr][sp * 4] = rq0;
    *(v4f*)&kl[sr + 32][sp * 4] = rk1;
    *(v4f*)&ql[sr + 32][sp * 4] = rq1;

    float a2s[HH];
    float asum = 0.f;
#pragma unroll
    for (int h = 0; h < HH; ++h) {
      float av = avec[h];
      a2s[h] = 2.0f * av;
      asum += av;
    }
    __syncthreads();

    int mg = tid >> 4, ng = tid & 15;
    const float* kvb[4];
    const float* qvb[4];
#pragma unroll
    for (int j = 0; j < 4; ++j) {
      kvb[j] = &kl[ng + 16 * j][0];
      qvb[j] = &ql[mg + 16 * j][0];
    }
    float acc[4][4];
#pragma unroll
    for (int i = 0; i < 4; ++i)
#pragma unroll
      for (int j = 0; j < 4; ++j) acc[i][j] = 0.f;

#pragma unroll
    for (int h4 = 0; h4 < 8; ++h4) {
      v4f kv[4], qv[4];
#pragma unroll
      for (int j = 0; j < 4; ++j) kv[j] = *(const v4f*)(kvb[j] + h4 * 4);
#pragma unroll
      for (int i = 0; i < 4; ++i) qv[i] = *(const v4f*)(qvb[i] + h4 * 4);
      float a0 = a2s[h4 * 4 + 0], a1 = a2s[h4 * 4 + 1];
      float a2 = a2s[h4 * 4 + 2], a3 = a2s[h4 * 4 + 3];
#pragma unroll
      for (int i = 0; i < 4; ++i)
#pragma unroll
        for (int j = 0; j < 4; ++j) {
          v4f f = kv[j] * qv[i] + 1.0f;
          // paired rcp: 2a0/f0 + 2a1/f1 = (a2s0*f1 + a2s1*f0) / (f0*f1)
          float den0 = f[0] * f[1], den1 = f[2] * f[3];
          float num0 = __builtin_fmaf(a0, f[1], a1 * f[0]);
          float num1 = __builtin_fmaf(a2, f[3], a3 * f[2]);
          acc[i][j] = __builtin_fmaf(num0, __builtin_amdgcn_rcpf(den0), acc[i][j]);
          acc[i][j] = __builtin_fmaf(num1, __builtin_amdgcn_rcpf(den1), acc[i][j]);
        }
    }
    unsigned short* eb = Et + ((size_t)b * GN + m0 + mg) * GN + n0 + ng;
#pragma unroll
    for (int i = 0; i < 4; ++i)
#pragma unroll
      for (int j = 0; j < 4; ++j)
        eb[(size_t)(16 * i) * GN + 16 * j] = (unsigned short)f2bf(asum - acc[i][j]);
  } else {
    // ================= transpose block (4 tiles) =================
    float (*t)[65] = (float (*)[65])smem;
#pragma unroll 1
    for (int l = 0; l < 4; ++l) {
      int tt = grp * 4 + l;
      int b = tt >> 6, rem = tt & 63;
      int c0 = (rem & 7) * 64, r0 = (rem >> 3) * 64;
      const float* ab = adj + (size_t)b * GN * GN;
      unsigned short* ob = adjT + (size_t)b * GN * GN;
      unsigned short* of = adjBF + (size_t)b * GN * GN;
#pragma unroll
      for (int k = 0; k < 4; ++k) {
        int v = tid + k * 256;
        int row = v >> 4, seg = v & 15;
        v4f f = *(const v4f*)(ab + (size_t)(r0 + row) * GN + c0 + seg * 4);
        t[row][seg * 4 + 0] = f[0];
        t[row][seg * 4 + 1] = f[1];
        t[row][seg * 4 + 2] = f[2];
        t[row][seg * 4 + 3] = f[3];
        v2u p = {pack2(f[0], f[1]), pack2(f[2], f[3])};
        *(v2u*)(of + (size_t)(r0 + row) * GN + c0 + seg * 4) = p;
      }
      __syncthreads();
      {
        int c = tid >> 2;
        int rs = (tid & 3) * 16;
        v4u p0, p1;
#pragma unroll
        for (int j = 0; j < 4; ++j) {
          p0[j] = pack2(t[rs + 2 * j][c], t[rs + 2 * j + 1][c]);
          p1[j] = pack2(t[rs + 8 + 2 * j][c], t[rs + 9 + 2 * j][c]);
        }
        unsigned short* dst = ob + (size_t)(c0 + c) * GN + r0 + rs;
        *(v4u*)dst = p0;
        *(v4u*)(dst + 8) = p1;
      }
      __syncthreads();
    }
  }
}

// ---------------- Stage 4/5: batched bf16 GEMM, 2-phase + XCD swizzle -------
#define SWZ(r, s) ((s) ^ ((r) & 7))

template <bool OUTF32>
__global__ __launch_bounds__(256) void gemm_bt(const unsigned short* __restrict__ A,
                                               const unsigned short* __restrict__ Bt,
                                               void* __restrict__ Cv) {
  __shared__ unsigned short At[2][128 * 64];  // 2 x 16 KiB
  __shared__ unsigned short Bs[2][128 * 64];
  int bid = blockIdx.x;
  int swz = (bid & 7) * 64 + (bid >> 3);  // XCD-chunked, bijective
  int b = swz >> 4;
  int row0 = ((swz >> 2) & 3) * 128;
  int col0 = (swz & 3) * 128;
  int tid = threadIdx.x, lane = tid & 63, wave = tid >> 6;
  int wr = wave >> 1, wc = wave & 1;
  const unsigned short* Ab = A + (size_t)b * GN * GN;
  const unsigned short* Bb = Bt + (size_t)b * GN * GN;

  v4f acc[4][4];
#pragma unroll
  for (int i = 0; i < 4; ++i)
#pragma unroll
    for (int j = 0; j < 4; ++j) acc[i][j] = (v4f){0.f, 0.f, 0.f, 0.f};

  int cc_r[4], cc_s[4];
#pragma unroll
  for (int i = 0; i < 4; ++i) {
    int c = i * 256 + tid;
    cc_r[i] = c >> 3;
    cc_s[i] = SWZ(c >> 3, c & 7);
  }

#define STAGE(buf, kt)                                                                   \
  {                                                                                      \
    _Pragma("unroll") for (int i = 0; i < 4; ++i) {                                      \
      const unsigned short* ga = Ab + (size_t)(row0 + cc_r[i]) * GN + (kt)*64 + cc_s[i] * 8; \
      const unsigned short* gb = Bb + (size_t)(col0 + cc_r[i]) * GN + (kt)*64 + cc_s[i] * 8; \
      GLOAD16(ga, (char*)&At[buf][0] + (i * 256 + wave * 64) * 16);                      \
      GLOAD16(gb, (char*)&Bs[buf][0] + (i * 256 + wave * 64) * 16);                      \
    }                                                                                    \
  }

#define COMPUTE(buf)                                                                     \
  {                                                                                      \
    int lr = lane & 15, s16 = lane >> 4;                                                 \
    _Pragma("unroll") for (int h = 0; h < 2; ++h) {                                      \
      int sl = h * 4 + s16;                                                              \
      v8bf af[4], bfv[4];                                                                \
      _Pragma("unroll") for (int i = 0; i < 4; ++i) {                                    \
        int r = wr * 64 + i * 16 + lr;                                                   \
        af[i] = *(const v8bf*)&At[buf][r * 64 + SWZ(r, sl) * 8];                         \
      }                                                                                  \
      _Pragma("unroll") for (int j = 0; j < 4; ++j) {                                    \
        int r = wc * 64 + j * 16 + lr;                                                   \
        bfv[j] = *(const v8bf*)&Bs[buf][r * 64 + SWZ(r, sl) * 8];                        \
      }                                                                                  \
      _Pragma("unroll") for (int i = 0; i < 4; ++i)                                      \
          _Pragma("unroll") for (int j = 0; j < 4; ++j) acc[i][j] =                      \
          __builtin_amdgcn_mfma_f32_16x16x32_bf16(af[i], bfv[j], acc[i][j], 0, 0, 0);    \
    }                                                                                    \
  }

  STAGE(0, 0);
  VMCNT0;
  __builtin_amdgcn_s_barrier();
#pragma unroll
  for (int kt = 0; kt < 7; ++kt) {
    int cur = kt & 1;
    STAGE(cur ^ 1, kt + 1);
    COMPUTE(cur);
    VMCNT0;
    __builtin_amdgcn_s_barrier();
  }
  COMPUTE(1);

  int lc = lane & 15;
  int lrow4 = (lane >> 4) * 4;
#pragma unroll
  for (int i = 0; i < 4; ++i) {
#pragma unroll
    for (int j = 0; j < 4; ++j) {
      int gr = row0 + wr * 64 + i * 16 + lrow4;
      int gc = col0 + wc * 64 + j * 16 + lc;
#pragma unroll
      for (int e = 0; e < 4; ++e) {
        float v = acc[i][j][e];
        if constexpr (OUTF32)
          ((float*)Cv)[(size_t)b * GN * GN + (size_t)(gr + e) * GN + gc] = v;
        else
          ((unsigned short*)Cv)[(size_t)b * GN * GN + (size_t)(gr + e) * GN + gc] =
              (unsigned short)f2bf(v);
      }
    }
  }
#undef STAGE
#undef COMPUTE
}

// ---------------- launch ----------------------------------------------------
extern "C" void kernel_launch(void* const* d_in, const int* in_sizes, int n_in,
                              void* d_out, int out_size, void* d_ws, size_t ws_size,
                              hipStream_t stream) {
  const float* receiver  = (const float*)d_in[0];
  const float* attendant = (const float*)d_in[1];
  const float* adj       = (const float*)d_in[2];
  const float* wq        = (const float*)d_in[3];
  const float* wk        = (const float*)d_in[4];
  const float* bias      = (const float*)d_in[5];
  const float* avec      = (const float*)d_in[6];
  float* out = (float*)d_out;

  char* ws = (char*)d_ws;
  float* ekbuf          = (float*)(ws);                          // 2 MiB
  float* eqbuf          = (float*)(ws + (2u << 20));             // 2 MiB
  unsigned short* Et    = (unsigned short*)(ws + (4u << 20));    // 16 MiB
  unsigned short* adjT  = (unsigned short*)(ws + (20u << 20));   // 16 MiB
  unsigned short* adjBF = (unsigned short*)(ws + (36u << 20));   // 16 MiB
  unsigned short* Tbuf  = (unsigned short*)(ws + (52u << 20));   // 16 MiB

  kq_kernel<<<dim3(2048), dim3(256), 0, stream>>>(receiver, attendant, wq, wk, bias,
                                                  ekbuf, eqbuf);
  prep2_kernel<<<dim3(2560), dim3(256), 0, stream>>>(adj, ekbuf, eqbuf, avec,
                                                     adjT, adjBF, Et);
  // T = adjBF @ Et^T  -> bf16
  gemm_bt<false><<<dim3(512), dim3(256), 0, stream>>>(adjBF, Et, Tbuf);
  // out = Tbuf @ adjT^T -> f32
  gemm_bt<true><<<dim3(512), dim3(256), 0, stream>>>(Tbuf, adjT, out);
}

// Round 12
// 76.167 us; speedup vs baseline: 1.0605x; 1.0296x over previous
//
#include <hip/hip_runtime.h>

#define GN 512
#define HH 32
#define DD 64

typedef float v4f __attribute__((ext_vector_type(4)));
typedef unsigned int v4u __attribute__((ext_vector_type(4)));
typedef u_int32_t u32;
typedef u32 v2u __attribute__((ext_vector_type(2)));
typedef __bf16 v8bf __attribute__((ext_vector_type(8)));

__device__ __forceinline__ u32 f2bf(float f) {
  u32 u = __builtin_bit_cast(u32, f);
  return (u + 0x7fffu + ((u >> 16) & 1u)) >> 16;
}
__device__ __forceinline__ u32 pack2(float a, float b) {
  return f2bf(a) | (f2bf(b) << 16);
}

#define GLOAD16(g, l)                                                              \
  __builtin_amdgcn_global_load_lds((const __attribute__((address_space(1))) u32*)(g), \
                                   (__attribute__((address_space(3))) u32*)(l), 16, 0, 0)
#define VMCNT0 asm volatile("s_waitcnt vmcnt(0)" ::: "memory")

// ---------------- Stage 1: projections -> exp space -------------------------
__global__ __launch_bounds__(256) void kq_kernel(const float* __restrict__ rec,
                                                 const float* __restrict__ att,
                                                 const float* __restrict__ wq,
                                                 const float* __restrict__ wk,
                                                 const float* __restrict__ bias,
                                                 float* __restrict__ ekbuf,
                                                 float* __restrict__ eqbuf) {
  __shared__ float rr[512], ra[512];
  int tid = threadIdx.x;
  size_t base = (size_t)blockIdx.x * 8;
  const float* gr = rec + base * DD;
  const float* ga = att + base * DD;
  rr[tid] = gr[tid]; rr[tid + 256] = gr[tid + 256];
  ra[tid] = ga[tid]; ra[tid + 256] = ga[tid + 256];
  __syncthreads();
  int r = tid >> 5, h = tid & 31;
  float sk = bias[h], sq = 0.f;
  const float* rrow = &rr[r * DD];
  const float* arow = &ra[r * DD];
#pragma unroll 8
  for (int d = 0; d < DD; ++d) {
    sk += rrow[d] * wk[d * HH + h];
    sq += arow[d] * wq[d * HH + h];
  }
  const float C = 2.8853900817779268f;  // 2*log2(e)
  ekbuf[(base + r) * HH + h] = __builtin_exp2f(C * sk);
  eqbuf[(base + r) * HH + h] = __builtin_exp2f(C * sq);
}

// ------- Stage 2+3: heterogeneous blocks — escore OR transpose --------------
// escore: thread owns 4 m-rows x 4 CONSECUTIVE n -> coalesced 8B Et stores;
// k-tile transposed in LDS (conflict-free kv b128), q row-major (broadcast).
__global__ __launch_bounds__(256) void prep2_kernel(const float* __restrict__ adj,
                                                    const float* __restrict__ ek,
                                                    const float* __restrict__ eq,
                                                    const float* __restrict__ avec,
                                                    unsigned short* __restrict__ adjT,
                                                    unsigned short* __restrict__ adjBF,
                                                    unsigned short* __restrict__ Et) {
  __shared__ __align__(16) float smem[4608];  // escore: klt|ql ; transpose: t[64][65]
  int tid = threadIdx.x;
  int bid = blockIdx.x;
  int type = bid % 5, grp = bid / 5;

  if (type < 4) {
    // ================= escore block =================
    float (*klt)[68] = (float (*)[68])smem;        // [32 h][64 n + 4 pad]
    float (*ql)[36] = (float (*)[36])&smem[2176];  // [64 m][32 h + 4 pad]
    int e = grp * 4 + type;
    int b = e >> 6, rem = e & 63;
    int n0 = (rem & 7) * 64, m0 = (rem >> 3) * 64;

    const float* kb = ek + ((size_t)b * GN + n0) * HH;
    const float* qb = eq + ((size_t)b * GN + m0) * HH;
    int sr = tid >> 3, sp = tid & 7;
    v4f rk0 = *(const v4f*)(kb + sr * HH + sp * 4);
    v4f rq0 = *(const v4f*)(qb + sr * HH + sp * 4);
    v4f rk1 = *(const v4f*)(kb + (sr + 32) * HH + sp * 4);
    v4f rq1 = *(const v4f*)(qb + (sr + 32) * HH + sp * 4);
    *(v4f*)&ql[sr][sp * 4] = rq0;
    *(v4f*)&ql[sr + 32][sp * 4] = rq1;
#pragma unroll
    for (int ee = 0; ee < 4; ++ee) {
      klt[sp * 4 + ee][sr] = rk0[ee];
      klt[sp * 4 + ee][sr + 32] = rk1[ee];
    }

    float a2s[HH];
    float asum = 0.f;
#pragma unroll
    for (int h = 0; h < HH; ++h) {
      float av = avec[h];
      a2s[h] = 2.0f * av;
      asum += av;
    }
    __syncthreads();

    int mg = tid >> 4, ng = tid & 15;  // rows m0+mg+16i ; cols n0+4ng..+3
    v4f acc[4];
#pragma unroll
    for (int i = 0; i < 4; ++i) acc[i] = (v4f){0.f, 0.f, 0.f, 0.f};

#pragma unroll
    for (int h4 = 0; h4 < 8; ++h4) {
      v4f kv[4], qv[4];
#pragma unroll
      for (int ee = 0; ee < 4; ++ee) kv[ee] = *(const v4f*)&klt[h4 * 4 + ee][4 * ng];
#pragma unroll
      for (int i = 0; i < 4; ++i) qv[i] = *(const v4f*)&ql[mg + 16 * i][h4 * 4];
      float a0 = a2s[h4 * 4 + 0], a1 = a2s[h4 * 4 + 1];
      float a2 = a2s[h4 * 4 + 2], a3 = a2s[h4 * 4 + 3];
#pragma unroll
      for (int i = 0; i < 4; ++i) {
        v4f f0 = kv[0] * qv[i][0] + 1.0f;
        v4f f1 = kv[1] * qv[i][1] + 1.0f;
        v4f f2 = kv[2] * qv[i][2] + 1.0f;
        v4f f3 = kv[3] * qv[i][3] + 1.0f;
        v4f den0 = f0 * f1, den1 = f2 * f3;
        v4f num0 = a0 * f1 + a1 * f0;
        v4f num1 = a2 * f3 + a3 * f2;
        v4f r0, r1;
#pragma unroll
        for (int ee = 0; ee < 4; ++ee) {
          r0[ee] = __builtin_amdgcn_rcpf(den0[ee]);
          r1[ee] = __builtin_amdgcn_rcpf(den1[ee]);
        }
        acc[i] += num0 * r0;
        acc[i] += num1 * r1;
      }
    }
#pragma unroll
    for (int i = 0; i < 4; ++i) {
      v4f s = asum - acc[i];
      v2u p = {pack2(s[0], s[1]), pack2(s[2], s[3])};
      *(v2u*)(Et + ((size_t)b * GN + m0 + mg + 16 * i) * GN + n0 + 4 * ng) = p;
    }
  } else {
    // ================= transpose block (4 tiles) =================
    float (*t)[65] = (float (*)[65])smem;
#pragma unroll 1
    for (int l = 0; l < 4; ++l) {
      int tt = grp * 4 + l;
      int b = tt >> 6, rem = tt & 63;
      int c0 = (rem & 7) * 64, r0 = (rem >> 3) * 64;
      const float* ab = adj + (size_t)b * GN * GN;
      unsigned short* ob = adjT + (size_t)b * GN * GN;
      unsigned short* of = adjBF + (size_t)b * GN * GN;
#pragma unroll
      for (int k = 0; k < 4; ++k) {
        int v = tid + k * 256;
        int row = v >> 4, seg = v & 15;
        v4f f = *(const v4f*)(ab + (size_t)(r0 + row) * GN + c0 + seg * 4);
        t[row][seg * 4 + 0] = f[0];
        t[row][seg * 4 + 1] = f[1];
        t[row][seg * 4 + 2] = f[2];
        t[row][seg * 4 + 3] = f[3];
        v2u p = {pack2(f[0], f[1]), pack2(f[2], f[3])};
        *(v2u*)(of + (size_t)(r0 + row) * GN + c0 + seg * 4) = p;
      }
      __syncthreads();
      {
        int c = tid >> 2;
        int rs = (tid & 3) * 16;
        v4u p0, p1;
#pragma unroll
        for (int j = 0; j < 4; ++j) {
          p0[j] = pack2(t[rs + 2 * j][c], t[rs + 2 * j + 1][c]);
          p1[j] = pack2(t[rs + 8 + 2 * j][c], t[rs + 9 + 2 * j][c]);
        }
        unsigned short* dst = ob + (size_t)(c0 + c) * GN + r0 + rs;
        *(v4u*)dst = p0;
        *(v4u*)(dst + 8) = p1;
      }
      __syncthreads();
    }
  }
}

// ---------------- Stage 4/5: batched bf16 GEMM (round-9 passing version) ----
// 128x128 tile, BK=64, 256 threads, double-buffered, grid 512, XCD swizzle.
#define SWZ(r, s) ((s) ^ ((r) & 7))

template <bool OUTF32>
__global__ __launch_bounds__(256) void gemm_bt(const unsigned short* __restrict__ A,
                                               const unsigned short* __restrict__ Bt,
                                               void* __restrict__ Cv) {
  __shared__ unsigned short At[2][128 * 64];  // 2 x 16 KiB
  __shared__ unsigned short Bs[2][128 * 64];
  int bid = blockIdx.x;
  int swz = (bid & 7) * 64 + (bid >> 3);  // XCD-chunked, bijective
  int b = swz >> 4;
  int row0 = ((swz >> 2) & 3) * 128;
  int col0 = (swz & 3) * 128;
  int tid = threadIdx.x, lane = tid & 63, wave = tid >> 6;
  int wr = wave >> 1, wc = wave & 1;
  const unsigned short* Ab = A + (size_t)b * GN * GN;
  const unsigned short* Bb = Bt + (size_t)b * GN * GN;

  v4f acc[4][4];
#pragma unroll
  for (int i = 0; i < 4; ++i)
#pragma unroll
    for (int j = 0; j < 4; ++j) acc[i][j] = (v4f){0.f, 0.f, 0.f, 0.f};

  int cc_r[4], cc_s[4];
#pragma unroll
  for (int i = 0; i < 4; ++i) {
    int c = i * 256 + tid;
    cc_r[i] = c >> 3;
    cc_s[i] = SWZ(c >> 3, c & 7);
  }

#define STAGE(buf, kt)                                                                   \
  {                                                                                      \
    _Pragma("unroll") for (int i = 0; i < 4; ++i) {                                      \
      const unsigned short* ga = Ab + (size_t)(row0 + cc_r[i]) * GN + (kt)*64 + cc_s[i] * 8; \
      const unsigned short* gb = Bb + (size_t)(col0 + cc_r[i]) * GN + (kt)*64 + cc_s[i] * 8; \
      GLOAD16(ga, (char*)&At[buf][0] + (i * 256 + wave * 64) * 16);                      \
      GLOAD16(gb, (char*)&Bs[buf][0] + (i * 256 + wave * 64) * 16);                      \
    }                                                                                    \
  }

#define COMPUTE(buf)                                                                     \
  {                                                                                      \
    int lr = lane & 15, s16 = lane >> 4;                                                 \
    _Pragma("unroll") for (int h = 0; h < 2; ++h) {                                      \
      int sl = h * 4 + s16;                                                              \
      v8bf af[4], bfv[4];                                                                \
      _Pragma("unroll") for (int i = 0; i < 4; ++i) {                                    \
        int r = wr * 64 + i * 16 + lr;                                                   \
        af[i] = *(const v8bf*)&At[buf][r * 64 + SWZ(r, sl) * 8];                         \
      }                                                                                  \
      _Pragma("unroll") for (int j = 0; j < 4; ++j) {                                    \
        int r = wc * 64 + j * 16 + lr;                                                   \
        bfv[j] = *(const v8bf*)&Bs[buf][r * 64 + SWZ(r, sl) * 8];                        \
      }                                                                                  \
      _Pragma("unroll") for (int i = 0; i < 4; ++i)                                      \
          _Pragma("unroll") for (int j = 0; j < 4; ++j) acc[i][j] =                      \
          __builtin_amdgcn_mfma_f32_16x16x32_bf16(af[i], bfv[j], acc[i][j], 0, 0, 0);    \
    }                                                                                    \
  }

  STAGE(0, 0);
  VMCNT0;
  __builtin_amdgcn_s_barrier();
#pragma unroll
  for (int kt = 0; kt < 7; ++kt) {
    int cur = kt & 1;
    STAGE(cur ^ 1, kt + 1);
    COMPUTE(cur);
    VMCNT0;
    __builtin_amdgcn_s_barrier();
  }
  COMPUTE(1);

  int lc = lane & 15;
  int lrow4 = (lane >> 4) * 4;
#pragma unroll
  for (int i = 0; i < 4; ++i) {
#pragma unroll
    for (int j = 0; j < 4; ++j) {
      int gr = row0 + wr * 64 + i * 16 + lrow4;
      int gc = col0 + wc * 64 + j * 16 + lc;
#pragma unroll
      for (int e = 0; e < 4; ++e) {
        float v = acc[i][j][e];
        if constexpr (OUTF32)
          ((float*)Cv)[(size_t)b * GN * GN + (size_t)(gr + e) * GN + gc] = v;
        else
          ((unsigned short*)Cv)[(size_t)b * GN * GN + (size_t)(gr + e) * GN + gc] =
              (unsigned short)f2bf(v);
      }
    }
  }
#undef STAGE
#undef COMPUTE
}

// ---------------- launch ----------------------------------------------------
extern "C" void kernel_launch(void* const* d_in, const int* in_sizes, int n_in,
                              void* d_out, int out_size, void* d_ws, size_t ws_size,
                              hipStream_t stream) {
  const float* receiver  = (const float*)d_in[0];
  const float* attendant = (const float*)d_in[1];
  const float* adj       = (const float*)d_in[2];
  const float* wq        = (const float*)d_in[3];
  const float* wk        = (const float*)d_in[4];
  const float* bias      = (const float*)d_in[5];
  const float* avec      = (const float*)d_in[6];
  float* out = (float*)d_out;

  char* ws = (char*)d_ws;
  float* ekbuf          = (float*)(ws);                          // 2 MiB
  float* eqbuf          = (float*)(ws + (2u << 20));             // 2 MiB
  unsigned short* Et    = (unsigned short*)(ws + (4u << 20));    // 16 MiB
  unsigned short* adjT  = (unsigned short*)(ws + (20u << 20));   // 16 MiB
  unsigned short* adjBF = (unsigned short*)(ws + (36u << 20));   // 16 MiB
  unsigned short* Tbuf  = (unsigned short*)(ws + (52u << 20));   // 16 MiB

  kq_kernel<<<dim3(2048), dim3(256), 0, stream>>>(receiver, attendant, wq, wk, bias,
                                                  ekbuf, eqbuf);
  prep2_kernel<<<dim3(2560), dim3(256), 0, stream>>>(adj, ekbuf, eqbuf, avec,
                                                     adjT, adjBF, Et);
  // T = adjBF @ Et^T  -> bf16
  gemm_bt<false><<<dim3(512), dim3(256), 0, stream>>>(adjBF, Et, Tbuf);
  // out = Tbuf @ adjT^T -> f32
  gemm_bt<true><<<dim3(512), dim3(256), 0, stream>>>(Tbuf, adjT, out);
}